// Round 1
// baseline (267.765 us; speedup 1.0000x reference)
//
#include <hip/hip_runtime.h>
#include <math.h>

// Tensor-field-network decoder: B=2, N=192, 3 conv layers (2 gated + 1 final).
// One block per (z,a) output atom. Strategy: per-pair T-columns (Y (x) CG (x) feat)
// and per-pair radial hidden h[32]; accumulate M[h][tcol] = sum_b h*T over all
// 192 neighbors, then contract with wout in a tiny epilogue. ~6.5x fewer flops
// than materializing per-pair radial weights Rw.

#define NN 192
#define BB 2
#define HHID 32
#define NBASIS 10

__device__ __forceinline__ float relu_r(float x) {
    return fmaxf(x, 0.0f) * 1.4142135623730951f;
}
__device__ __forceinline__ float sigmoid_r(float x) {
    return (1.0f / (1.0f + expf(-x))) * 1.84623f;
}

template <int LAYER>
__global__ __launch_bounds__(256) void tfn_layer(
    const float* __restrict__ geo,   // [B,N,3]
    const float* __restrict__ fin0,  // L0: features [B,N,16]; else f0 [B,N,16]
    const float* __restrict__ fin1,  // L1/2: f1 [B,N,8,3]
    const float* __restrict__ w0,    // [10,32]
    const float* __restrict__ b0g,   // [32]
    const float* __restrict__ wout,  // [32, TW]
    float* __restrict__ o0,          // L0/1: f0' [B,N,16]; L2: out [B,N,8]
    float* __restrict__ o1)          // L0/1: f1' [B,N,8,3]
{
    constexpr int TC   = (LAYER == 0) ? 64 : 144;               // T columns
    constexpr int TW   = (LAYER == 0) ? 512 : (LAYER == 1 ? 896 : 128);
    constexpr int CPT  = TC / 8;    // M cols per thread (M regs)
    constexpr int CPTT = TC / 16;   // T cols per thread in staging

    const int tid = threadIdx.x;
    const int blk = blockIdx.x;
    const int z = blk / NN, a = blk % NN;

    __shared__ float geoL[NN * 3];
    __shared__ float f0L[NN * 16];
    __shared__ float f1L[(LAYER == 0) ? 1 : (NN * 24)];
    __shared__ float w0L[NBASIS * HHID];
    __shared__ float b0L[HHID];
    __shared__ float YC[16 * 8];       // Y1[3], Y2[5] per b in chunk
    __shared__ float basC[16 * NBASIS];
    __shared__ float hC[16 * HHID];
    __shared__ float tC[16 * TC];
    __shared__ float Mlds[HHID * TC];
    __shared__ float outS[32];

    const float s = 0.07216878364870323f;  // 1/sqrt(192)

    for (int i = tid; i < NN * 3; i += 256) geoL[i] = geo[z * NN * 3 + i];
    for (int i = tid; i < NN * 16; i += 256) {
        float v = fin0[z * NN * 16 + i];
        if (LAYER == 0) v *= s;  // features scaled on load
        f0L[i] = v;
    }
    if constexpr (LAYER != 0) {
        for (int i = tid; i < NN * 24; i += 256) f1L[i] = fin1[z * NN * 24 + i];
    }
    for (int i = tid; i < NBASIS * HHID; i += 256) w0L[i] = w0[i];
    if (tid < HHID) b0L[tid] = b0g[tid];
    __syncthreads();

    const float ax = geoL[a * 3 + 0], ay = geoL[a * 3 + 1], az = geoL[a * 3 + 2];

    float Macc[CPT];
#pragma unroll
    for (int j = 0; j < CPT; ++j) Macc[j] = 0.0f;
    const int hh  = tid >> 3;
    const int cg0 = (tid & 7) * CPT;

    const float inv_sqrt10 = 0.31622776601683794f;

    for (int cb = 0; cb < NN / 16; ++cb) {
        // ---- per-b precompute: radial basis + spherical harmonics ----
        {
            const int bl = tid & 15, item = tid >> 4;
            const int b = cb * 16 + bl;
            float rx = ax - geoL[b * 3 + 0];
            float ry = ay - geoL[b * 3 + 1];
            float rz = az - geoL[b * 3 + 2];
            float r2 = rx * rx + ry * ry + rz * rz + 1e-12f;
            float r = sqrtf(r2);
            float inv = 1.0f / fmaxf(r, 1e-6f);
            float ux = rx * inv, uy = ry * inv, uz = rz * inv;
            if (item < NBASIS) {
                float dg = r * 2.25f - (float)item;  // (r - k*step)/step, step=4/9
                float bas = 0.0f;
                if (fabsf(dg) < 1.0f) {
                    float cc = cosf(1.5707963267948966f * dg);
                    bas = cc * cc;
                }
                basC[bl * NBASIS + item] = bas;
            } else if (item == 10) {
                YC[bl * 8 + 0] = 0.4886025119029199f * uy;
                YC[bl * 8 + 1] = 0.4886025119029199f * uz;
                YC[bl * 8 + 2] = 0.4886025119029199f * ux;
            } else if (item == 11) {
                YC[bl * 8 + 3] = 1.0925484305920792f * ux * uy;
                YC[bl * 8 + 4] = 1.0925484305920792f * uy * uz;
                YC[bl * 8 + 5] = 0.31539156525252005f * (2.0f * uz * uz - ux * ux - uy * uy);
                YC[bl * 8 + 6] = 1.0925484305920792f * ux * uz;
                YC[bl * 8 + 7] = 0.5462742152960396f * (ux * ux - uy * uy);
            }
        }
        __syncthreads();

        // ---- hidden layer h = relu_r(basis @ (w0/sqrt(10)) + b0) : 16x32 ----
#pragma unroll
        for (int rep = 0; rep < 2; ++rep) {
            int idx = tid + rep * 256;
            int bl = idx >> 5, h2 = idx & 31;
            float su = 0.0f;
#pragma unroll
            for (int k = 0; k < NBASIS; ++k) su += basC[bl * NBASIS + k] * w0L[k * HHID + h2];
            hC[bl * HHID + h2] = relu_r(su * inv_sqrt10 + b0L[h2]);
        }

        // ---- T columns: 16 b x TC ----
        {
            const int bl = tid >> 4, cg = tid & 15;
            const int b = cb * 16 + bl;
            const float* Yb = &YC[bl * 8];
#pragma unroll
            for (int jj = 0; jj < CPTT; ++jj) {
                int c = cg * CPTT + jj;
                float val;
                if constexpr (LAYER == 0) {
                    if (c < 16) {
                        val = 0.28209479177387814f * f0L[b * 16 + c];            // (0,0,0)
                    } else {
                        int q = c - 16, v = q / 3, i2 = q % 3;                   // (1,0,1)
                        val = Yb[i2] * f0L[b * 16 + v] * 0.5773502691896258f;
                    }
                } else {
                    if (c < 16) {
                        val = 0.28209479177387814f * f0L[b * 16 + c];            // (0,0,0)
                    } else if (c < 24) {
                        int v = c - 16;                                          // (0,1,1)
                        const float* f = &f1L[(b * 8 + v) * 3];
                        val = (f[0] * Yb[0] + f[1] * Yb[1] + f[2] * Yb[2]) * 0.5773502691896258f;
                    } else if (c < 72) {
                        int q = c - 24, v = q / 3, i2 = q % 3;                   // (1,0,1)
                        val = Yb[i2] * f0L[b * 16 + v] * 0.5773502691896258f;
                    } else if (c < 96) {
                        int q = c - 72, v = q / 3, i2 = q % 3;                   // (1,1,0)
                        val = f1L[(b * 8 + v) * 3 + i2] * (0.28209479177387814f * 0.5773502691896258f);
                    } else if (c < 120) {
                        int q = c - 96, v = q / 3, i2 = q % 3;                   // (1,1,1) cross
                        const float* f = &f1L[(b * 8 + v) * 3];
                        int i1 = (i2 + 1) % 3, i3 = (i2 + 2) % 3;
                        val = (f[i1] * Yb[i3] - f[i3] * Yb[i1]) * 0.4082482904638631f;
                    } else {
                        int q = c - 120, v = q / 3, i2 = q % 3;                  // (1,1,2)
                        const float* f = &f1L[(b * 8 + v) * 3];
                        const float D = 0.31622776601683794f;   // d/||m||
                        const float Bc = 0.18257418583505536f;  // b/||m||
                        float Y20 = Yb[3], Y21 = Yb[4], Y22 = Yb[5], Y23 = Yb[6], Y24 = Yb[7];
                        if (i2 == 0)      val = D * (Y20 * f[2] + Y21 * f[1]) - (Bc * Y22 + D * Y24) * f[0];
                        else if (i2 == 1) val = D * (Y21 * f[0] + Y23 * f[2]) + 2.0f * Bc * Y22 * f[1];
                        else              val = D * (Y20 * f[0] + Y23 * f[1] + Y24 * f[2]) - Bc * Y22 * f[2];
                    }
                }
                tC[bl * TC + c] = val;
            }
        }
        __syncthreads();

        // ---- rank-16 update of M ----
#pragma unroll 4
        for (int bl = 0; bl < 16; ++bl) {
            float hv = hC[bl * HHID + hh];
#pragma unroll
            for (int j = 0; j < CPT; ++j) Macc[j] += hv * tC[bl * TC + cg0 + j];
        }
        __syncthreads();
    }

#pragma unroll
    for (int j = 0; j < CPT; ++j) Mlds[hh * TC + cg0 + j] = Macc[j];
    __syncthreads();

    // ---- epilogue: contract with wout, normalize, gate, store ----
    const float i32 = 0.1767766952966369f;  // 1/sqrt(32)

    if constexpr (LAYER == 0) {
        const float sc = i32 * 0.25f;  // (1/sqrt(H)) * (1/sqrt(16*1))
        float o1v = 0.0f;
        if (tid < 24) {
            float acc = 0.0f;
            for (int h2 = 0; h2 < 32; ++h2) {
                const float* wr = &wout[h2 * TW + tid * 16];
                const float* mr = &Mlds[h2 * TC];
#pragma unroll
                for (int v = 0; v < 16; ++v) acc += wr[v] * mr[v];
            }
            outS[tid] = acc * sc;
        } else if (tid >= 32 && tid < 56) {
            int idx = tid - 32, u = idx / 3, i2 = idx % 3;
            float acc = 0.0f;
            for (int h2 = 0; h2 < 32; ++h2) {
                const float* wr = &wout[h2 * TW + 384 + u * 16];
                const float* mr = &Mlds[h2 * TC + 16 + i2];
#pragma unroll
                for (int v = 0; v < 16; ++v) acc += wr[v] * mr[v * 3];
            }
            o1v = acc * sc;
        }
        __syncthreads();
        if (tid < 16) {
            o0[(z * NN + a) * 16 + tid] = relu_r(outS[tid]) * s;
        } else if (tid >= 32 && tid < 56) {
            int idx = tid - 32, u = idx / 3, i2 = idx % 3;
            float g = sigmoid_r(outS[16 + u]);
            o1[((z * NN + a) * 8 + u) * 3 + i2] = o1v * g * s;
        }
    } else if constexpr (LAYER == 1) {
        float o1v = 0.0f;
        if (tid < 24) {
            float aA = 0.0f, aB = 0.0f;
            for (int h2 = 0; h2 < 32; ++h2) {
                const float* wr = &wout[h2 * TW];
                const float* mr = &Mlds[h2 * TC];
#pragma unroll
                for (int v = 0; v < 16; ++v) aA += wr[tid * 16 + v] * mr[v];
#pragma unroll
                for (int v = 0; v < 8; ++v) aB += wr[384 + tid * 8 + v] * mr[16 + v];
            }
            outS[tid] = (aA * i32 + aB * 0.25f) * i32;
        } else if (tid >= 32 && tid < 56) {
            int idx = tid - 32, u = idx / 3, i2 = idx % 3;
            float aA = 0.0f, aB = 0.0f;
            for (int h2 = 0; h2 < 32; ++h2) {
                const float* wr = &wout[h2 * TW];
                const float* mr = &Mlds[h2 * TC];
#pragma unroll
                for (int v = 0; v < 16; ++v) aA += wr[576 + u * 16 + v] * mr[24 + v * 3 + i2];
#pragma unroll
                for (int v = 0; v < 8; ++v)
                    aB += wr[704 + u * 8 + v] * mr[72 + v * 3 + i2]
                        + wr[768 + u * 8 + v] * mr[96 + v * 3 + i2]
                        + wr[832 + u * 8 + v] * mr[120 + v * 3 + i2];
            }
            o1v = (aA * 0.125f + aB * i32) * i32;
        }
        __syncthreads();
        if (tid < 16) {
            o0[(z * NN + a) * 16 + tid] = relu_r(outS[tid]) * s;
        } else if (tid >= 32 && tid < 56) {
            int idx = tid - 32, u = idx / 3, i2 = idx % 3;
            float g = sigmoid_r(outS[16 + u]);
            o1[((z * NN + a) * 8 + u) * 3 + i2] = o1v * g * s;
        }
    } else {  // LAYER == 2: final conv, no gating, no *s; write [B,N,2,4] interleaved
        if (tid < 2) {
            float aA = 0.0f, aB = 0.0f;
            for (int h2 = 0; h2 < 32; ++h2) {
                const float* wr = &wout[h2 * TW];
                const float* mr = &Mlds[h2 * TC];
#pragma unroll
                for (int v = 0; v < 16; ++v) aA += wr[tid * 16 + v] * mr[v];
#pragma unroll
                for (int v = 0; v < 8; ++v) aB += wr[32 + tid * 8 + v] * mr[16 + v];
            }
            o0[(z * NN + a) * 8 + tid * 4] = (aA * i32 + aB * 0.25f) * i32;
        } else if (tid >= 32 && tid < 38) {
            int idx = tid - 32, u = idx / 3, i2 = idx % 3;
            float aA = 0.0f, aB = 0.0f;
            for (int h2 = 0; h2 < 32; ++h2) {
                const float* wr = &wout[h2 * TW];
                const float* mr = &Mlds[h2 * TC];
#pragma unroll
                for (int v = 0; v < 16; ++v) aA += wr[48 + u * 16 + v] * mr[24 + v * 3 + i2];
#pragma unroll
                for (int v = 0; v < 8; ++v)
                    aB += wr[80 + u * 8 + v] * mr[72 + v * 3 + i2]
                        + wr[96 + u * 8 + v] * mr[96 + v * 3 + i2]
                        + wr[112 + u * 8 + v] * mr[120 + v * 3 + i2];
            }
            o0[(z * NN + a) * 8 + u * 4 + 1 + i2] = (aA * 0.125f + aB * i32) * i32;
        }
    }
}

extern "C" void kernel_launch(void* const* d_in, const int* in_sizes, int n_in,
                              void* d_out, int out_size, void* d_ws, size_t ws_size,
                              hipStream_t stream) {
    const float* features = (const float*)d_in[0];
    const float* geometry = (const float*)d_in[1];
    const float* c0w0   = (const float*)d_in[2];
    const float* c0b0   = (const float*)d_in[3];
    const float* c0wout = (const float*)d_in[4];
    const float* c1w0   = (const float*)d_in[5];
    const float* c1b0   = (const float*)d_in[6];
    const float* c1wout = (const float*)d_in[7];
    const float* c2w0   = (const float*)d_in[8];
    const float* c2b0   = (const float*)d_in[9];
    const float* c2wout = (const float*)d_in[10];
    float* out = (float*)d_out;

    float* ws  = (float*)d_ws;
    float* f0a = ws;                 // [B*N*16]
    float* f1a = f0a + BB * NN * 16; // [B*N*8*3]
    float* f0b = f1a + BB * NN * 24;
    float* f1b = f0b + BB * NN * 16;

    dim3 grid(BB * NN), block(256);
    hipLaunchKernelGGL((tfn_layer<0>), grid, block, 0, stream,
                       geometry, features, nullptr, c0w0, c0b0, c0wout, f0a, f1a);
    hipLaunchKernelGGL((tfn_layer<1>), grid, block, 0, stream,
                       geometry, f0a, f1a, c1w0, c1b0, c1wout, f0b, f1b);
    hipLaunchKernelGGL((tfn_layer<2>), grid, block, 0, stream,
                       geometry, f0b, f1b, c2w0, c2b0, c2wout, out, nullptr);
}